// Round 16
// baseline (169.518 us; speedup 1.0000x reference)
//
#include <hip/hip_runtime.h>
#include <stdint.h>

typedef unsigned short u16;
typedef __attribute__((ext_vector_type(8))) short bf16x8;
typedef __attribute__((ext_vector_type(4))) float f32x4;

__device__ __forceinline__ float bf2f(u16 u){
  union { uint32_t i; float f; } v; v.i = ((uint32_t)u) << 16; return v.f;
}
__device__ __forceinline__ u16 f2bf(float f){
  union { float fl; uint32_t i; } v; v.fl = f;
  uint32_t r = v.i + 0x7FFFu + ((v.i >> 16) & 1u);
  return (u16)(r >> 16);
}
__device__ __forceinline__ uint32_t cvt_pk_bf16(float lo, float hi){
  uint32_t r;
  asm("v_cvt_pk_bf16_f32 %0, %1, %2" : "=v"(r) : "v"(lo), "v"(hi));
  return r;
}
__device__ __forceinline__ f32x4 mfma16(bf16x8 a, bf16x8 b, f32x4 c){
  return __builtin_amdgcn_mfma_f32_16x16x32_bf16(a, b, c, 0, 0, 0);
}
// async global->LDS, 16 B per lane; LDS dest is wave-uniform base + lane*16
__device__ __forceinline__ void gload16(const u16* g, u16* l){
  __builtin_amdgcn_global_load_lds((const __attribute__((address_space(1))) void*)g,
                                   (__attribute__((address_space(3))) void*)l, 16, 0, 0);
}

// ---------------- elementwise convert f32 -> bf16 (with scale fold) ----------------
__global__ __launch_bounds__(256) void k_conv_bf(const float* __restrict__ in, u16* __restrict__ out, int n, float scale){
  int i = (blockIdx.x * 256 + threadIdx.x) * 4;
  if (i >= n) return;
  float4 v = *(const float4*)(in + i);
  ushort4 o; o.x=f2bf(v.x*scale); o.y=f2bf(v.y*scale); o.z=f2bf(v.z*scale); o.w=f2bf(v.w*scale);
  *(ushort4*)(out + i) = o;
}

// ---------- transpose + convert: in[R][C] f32 -> out[C][R] bf16 ----------
__global__ __launch_bounds__(256) void k_transp(const float* __restrict__ in, u16* __restrict__ out, int R, int C){
  __shared__ u16 tile[64][68];
  int c0 = blockIdx.x * 64, r0 = blockIdx.y * 64;
  int tr = threadIdx.x >> 4;           // 0..15
  int tc = (threadIdx.x & 15) * 4;     // 0..60
  for (int rr = 0; rr < 4; rr++){
    int r = rr * 16 + tr;
    float4 v = *(const float4*)(in + (size_t)(r0 + r) * C + c0 + tc);
    ushort4 o; o.x=f2bf(v.x); o.y=f2bf(v.y); o.z=f2bf(v.z); o.w=f2bf(v.w);
    *(ushort4*)&tile[r][tc] = o;
  }
  __syncthreads();
  for (int rr = 0; rr < 4; rr++){
    int oc = rr * 16 + tr;             // original col = out row
    ushort4 o;
    o.x = tile[tc+0][oc]; o.y = tile[tc+1][oc]; o.z = tile[tc+2][oc]; o.w = tile[tc+3][oc];
    *(ushort4*)(out + (size_t)(c0 + oc) * R + r0 + tc) = o;
  }
}

// ---------------- LayerNorm: x[16384][512] f32 -> xn bf16 ----------------
__global__ __launch_bounds__(128) void k_ln(const float* __restrict__ x, const float* __restrict__ g,
                                            const float* __restrict__ b, u16* __restrict__ xn){
  int row = blockIdx.x;
  int t = threadIdx.x;
  float4 v = *(const float4*)(x + (size_t)row * 512 + t * 4);
  float s = v.x + v.y + v.z + v.w;
  float q = v.x*v.x + v.y*v.y + v.z*v.z + v.w*v.w;
  for (int o = 32; o > 0; o >>= 1){ s += __shfl_down(s, o); q += __shfl_down(q, o); }
  __shared__ float red[4];
  if ((t & 63) == 0){ red[(t >> 6) * 2] = s; red[(t >> 6) * 2 + 1] = q; }
  __syncthreads();
  float mu  = (red[0] + red[2]) * (1.0f/512.0f);
  float var = (red[1] + red[3]) * (1.0f/512.0f) - mu * mu;
  float rs = rsqrtf(var + 1e-5f);
  float4 gv = *(const float4*)(g + t * 4);
  float4 bv = *(const float4*)(b + t * 4);
  ushort4 o;
  o.x = f2bf((v.x - mu) * rs * gv.x + bv.x);
  o.y = f2bf((v.y - mu) * rs * gv.y + bv.y);
  o.z = f2bf((v.z - mu) * rs * gv.z + bv.z);
  o.w = f2bf((v.w - mu) * rs * gv.w + bv.w);
  *(ushort4*)(xn + (size_t)row * 512 + t * 4) = o;
}

// ======== 256x128-tile, BK=32, counted-vmcnt GEMM (8 waves, 48KB LDS) =========
// Row = 32 cols = 4 x 16B blocks. Storage position of logical block b in row r
// is b ^ ((r>>1)&3). gload_lds writes lane l -> row base+(l>>2), pos l&3, so the
// per-lane GLOBAL source pre-applies: blkSrc = (l&3) ^ ((l>>3)&3). Reads use
// xo = (q4 ^ ((lr>>1)&3))*8 (row-tile-independent since tiles are 16-aligned).

// ------- QKV GEMM: C = A * Bt^T; V-third also scattered transposed into vT ------
__global__ __launch_bounds__(512) void k_gemm_qkv(const u16* __restrict__ A, const u16* __restrict__ Bt,
                                                  u16* __restrict__ C, u16* __restrict__ vT){
  __shared__ u16 aL[2][256 * 32];
  __shared__ u16 bL[2][128 * 32];
  int m0 = blockIdx.x * 256, n0 = blockIdx.y * 128;
  int t = threadIdx.x, w = t >> 6, l = t & 63;
  int wm = (w >> 1) * 64, wn = (w & 1) * 64;   // 4M x 2N wave grid
  int lr = l & 15, q4 = l >> 4;
  int blkSrc = (l & 3) ^ ((l >> 3) & 3);
  const u16* gA = A  + (size_t)(m0 + (l >> 2)) * 512 + blkSrc * 8;
  const u16* gB = Bt + (size_t)(n0 + (l >> 2)) * 512 + blkSrc * 8;
  int xo = (q4 ^ ((lr >> 1) & 3)) * 8;
  f32x4 acc[4][4];
  for (int i=0;i<4;i++) for (int j=0;j<4;j++) acc[i][j] = {0.f,0.f,0.f,0.f};

  auto stage = [&](int buf, int k0){
    #pragma unroll
    for (int p = 0; p < 2; p++)
      gload16(gA + (size_t)((w*2+p)*16)*512 + k0, &aL[buf][((w*2+p)*16) * 32]);
    gload16(gB + (size_t)(w*16)*512 + k0, &bL[buf][(w*16) * 32]);
  };
  auto comp = [&](const u16* ab, const u16* bb){
    bf16x8 av[4], bv[4];
    #pragma unroll
    for (int mt=0;mt<4;mt++) av[mt] = *(const bf16x8*)&ab[(wm + mt*16 + lr)*32 + xo];
    #pragma unroll
    for (int nt=0;nt<4;nt++) bv[nt] = *(const bf16x8*)&bb[(wn + nt*16 + lr)*32 + xo];
    #pragma unroll
    for (int mt=0;mt<4;mt++)
      #pragma unroll
      for (int nt=0;nt<4;nt++)
        acc[mt][nt] = mfma16(av[mt], bv[nt], acc[mt][nt]);
  };

  // prologue: K-tiles 0 and 1 in flight (3 loads each); wait for tile 0
  stage(0, 0);
  stage(1, 32);
  asm volatile("s_waitcnt vmcnt(3)" ::: "memory");
  __builtin_amdgcn_s_barrier();
  asm volatile("" ::: "memory");
  int cur = 0;
  #pragma unroll
  for (int tk = 0; tk < 16; tk++){
    comp(&aL[cur][0], &bL[cur][0]);
    if (tk < 15){
      __builtin_amdgcn_s_barrier();            // all waves done reading cur
      if (tk + 2 < 16){
        stage(cur, (tk + 2) * 32);             // refill cur (3 new loads)
        asm volatile("s_waitcnt vmcnt(3)" ::: "memory");  // tile tk+1 landed
      } else {
        asm volatile("s_waitcnt vmcnt(0)" ::: "memory");  // last tile landed
      }
      __builtin_amdgcn_s_barrier();            // all waves' loads landed
      asm volatile("" ::: "memory");
    }
    cur ^= 1;
  }

  int rr = q4 * 4, cc = lr;
  bool isV = (n0 >= 1024);
  for (int mt=0;mt<4;mt++) for (int nt=0;nt<4;nt++){
    int r = m0 + wm + mt*16 + rr;
    int c = n0 + wn + nt*16 + cc;
    ushort4 o;
    o.x = f2bf(acc[mt][nt][0]); o.y = f2bf(acc[mt][nt][1]);
    o.z = f2bf(acc[mt][nt][2]); o.w = f2bf(acc[mt][nt][3]);
    C[(size_t)(r+0) * 1536 + c] = o.x;
    C[(size_t)(r+1) * 1536 + c] = o.y;
    C[(size_t)(r+2) * 1536 + c] = o.z;
    C[(size_t)(r+3) * 1536 + c] = o.w;
    if (isV) *(ushort4*)(vT + ((size_t)(c - 1024) << 14) + r) = o;
  }
}

// ------- out GEMM: y = A[16384][512]*Bt[512][512]^T + bias + x (f32) ----------
__global__ __launch_bounds__(512) void k_gemm_out(const u16* __restrict__ A, const u16* __restrict__ Bt,
                                                  const float* __restrict__ x, const float* __restrict__ bias,
                                                  float* __restrict__ y){
  __shared__ u16 aL[2][256 * 32];
  __shared__ u16 bL[2][128 * 32];
  int m0 = blockIdx.x * 256, n0 = blockIdx.y * 128;
  int t = threadIdx.x, w = t >> 6, l = t & 63;
  int wm = (w >> 1) * 64, wn = (w & 1) * 64;
  int lr = l & 15, q4 = l >> 4;
  int blkSrc = (l & 3) ^ ((l >> 3) & 3);
  const u16* gA = A  + (size_t)(m0 + (l >> 2)) * 512 + blkSrc * 8;
  const u16* gB = Bt + (size_t)(n0 + (l >> 2)) * 512 + blkSrc * 8;
  int xo = (q4 ^ ((lr >> 1) & 3)) * 8;
  f32x4 acc[4][4];
  for (int i=0;i<4;i++) for (int j=0;j<4;j++) acc[i][j] = {0.f,0.f,0.f,0.f};

  auto stage = [&](int buf, int k0){
    #pragma unroll
    for (int p = 0; p < 2; p++)
      gload16(gA + (size_t)((w*2+p)*16)*512 + k0, &aL[buf][((w*2+p)*16) * 32]);
    gload16(gB + (size_t)(w*16)*512 + k0, &bL[buf][(w*16) * 32]);
  };
  auto comp = [&](const u16* ab, const u16* bb){
    bf16x8 av[4], bv[4];
    #pragma unroll
    for (int mt=0;mt<4;mt++) av[mt] = *(const bf16x8*)&ab[(wm + mt*16 + lr)*32 + xo];
    #pragma unroll
    for (int nt=0;nt<4;nt++) bv[nt] = *(const bf16x8*)&bb[(wn + nt*16 + lr)*32 + xo];
    #pragma unroll
    for (int mt=0;mt<4;mt++)
      #pragma unroll
      for (int nt=0;nt<4;nt++)
        acc[mt][nt] = mfma16(av[mt], bv[nt], acc[mt][nt]);
  };

  stage(0, 0);
  stage(1, 32);
  asm volatile("s_waitcnt vmcnt(3)" ::: "memory");
  __builtin_amdgcn_s_barrier();
  asm volatile("" ::: "memory");
  int cur = 0;
  #pragma unroll
  for (int tk = 0; tk < 16; tk++){
    comp(&aL[cur][0], &bL[cur][0]);
    if (tk < 15){
      __builtin_amdgcn_s_barrier();
      if (tk + 2 < 16){
        stage(cur, (tk + 2) * 32);
        asm volatile("s_waitcnt vmcnt(3)" ::: "memory");
      } else {
        asm volatile("s_waitcnt vmcnt(0)" ::: "memory");
      }
      __builtin_amdgcn_s_barrier();
      asm volatile("" ::: "memory");
    }
    cur ^= 1;
  }

  int rr = q4 * 4, cc = lr;
  for (int mt=0;mt<4;mt++) for (int nt=0;nt<4;nt++)
    for (int j=0;j<4;j++){
      int r = m0 + wm + mt*16 + rr + j;
      int c = n0 + wn + nt*16 + cc;
      y[(size_t)r * 512 + c] = acc[mt][nt][j] + bias[c] + x[(size_t)r * 512 + c];
    }
}

// ------- agent aggregation (attn1 + agent_v): 2 agent-tiles per block ----------
// 512 blocks; swizzle puts the 4 blocks sharing one (h,chunk) K/V panel on one
// XCD. Per sub: 32 MFMA/wave between barriers; staging traffic halved vs 1-tile.
__global__ __launch_bounds__(256) void k_agent_agg(const u16* __restrict__ agbf, const u16* __restrict__ qkv,
                                                   const u16* __restrict__ vT,
                                                   float* __restrict__ nump, float* __restrict__ denp){
  int L = blockIdx.x;
  int g = (L >> 5) * 8 + (L & 7);      // group = h*16 + ch  (128 groups)
  int m = (L >> 3) & 3;                // atile-pair (0..3)
  int h = g >> 4, ch = g & 15, a0 = m * 128;

  __shared__ u16 ag[128][68];
  __shared__ u16 kt[64][68];
  __shared__ u16 vt[64][68];
  __shared__ u16 pt[128][68];
  __shared__ float dnf[4][128];
  int t = threadIdx.x, w = t >> 6, l = t & 63;
  int lr = l & 15, q4 = l >> 4;

  // agent pair: 128 rows, loaded once (sr/sc map, 2 rows per thread)
  int sr = t >> 2, sc = (t & 3) * 16;
  {
    uint4 a0v = *(const uint4*)(agbf + (size_t)(h * 512 + a0 + sr) * 64 + sc);
    uint4 a1v = *(const uint4*)(agbf + (size_t)(h * 512 + a0 + sr) * 64 + sc + 8);
    uint4 a2v = *(const uint4*)(agbf + (size_t)(h * 512 + a0 + 64 + sr) * 64 + sc);
    uint4 a3v = *(const uint4*)(agbf + (size_t)(h * 512 + a0 + 64 + sr) * 64 + sc + 8);
    *(uint4*)&ag[sr][sc]          = a0v;
    *(uint4*)&ag[sr][sc + 8]      = a1v;
    *(uint4*)&ag[64 + sr][sc]     = a2v;
    *(uint4*)&ag[64 + sr][sc + 8] = a3v;
  }

  size_t nbase = (size_t)ch * 1024;
  const u16* kp = qkv + 512 + h * 64;
  const u16* vp = vT + ((size_t)(h * 64 + sr) << 14);

  f32x4 acc2[8];                       // C[a(8 tiles)][d-stripe w*16]
  #pragma unroll
  for (int i=0;i<8;i++) acc2[i] = {0.f,0.f,0.f,0.f};
  float den[8] = {0.f,0.f,0.f,0.f,0.f,0.f,0.f,0.f};

  for (int sub = 0; sub < 16; sub++){
    size_t n0 = nbase + sub * 64;
    __syncthreads();                   // protect kt/vt/pt from previous readers
    {
      uint4 rk0 = *(const uint4*)(kp + (n0 + sr) * 1536 + sc);
      uint4 rk1 = *(const uint4*)(kp + (n0 + sr) * 1536 + sc + 8);
      uint4 rv0 = *(const uint4*)(vp + n0 + sc);
      uint4 rv1 = *(const uint4*)(vp + n0 + sc + 8);
      *(uint4*)&kt[sr][sc]     = rk0;
      *(uint4*)&kt[sr][sc + 8] = rk1;
      *(uint4*)&vt[sr][sc]     = rv0;
      *(uint4*)&vt[sr][sc + 8] = rv1;
    }
    __syncthreads();

    // S^T: a = nt*16+lr (col, 8 tiles), n = w*16 + q4*4 + j (row)
    f32x4 s[8];
    #pragma unroll
    for (int nt=0;nt<8;nt++) s[nt] = {0.f,0.f,0.f,0.f};
    #pragma unroll
    for (int kk = 0; kk < 64; kk += 32){
      int kb = kk + q4 * 8;
      bf16x8 kf = *(const bf16x8*)&kt[w*16 + lr][kb];
      #pragma unroll
      for (int nt=0;nt<8;nt++){
        bf16x8 af = *(const bf16x8*)&ag[nt*16 + lr][kb];
        s[nt] = mfma16(kf, af, s[nt]);
      }
    }
    // exp2 + pack -> pt[a][n]; den accumulates in f32 regs
    #pragma unroll
    for (int nt=0;nt<8;nt++){
      float e0 = __builtin_amdgcn_exp2f(s[nt][0]);
      float e1 = __builtin_amdgcn_exp2f(s[nt][1]);
      float e2 = __builtin_amdgcn_exp2f(s[nt][2]);
      float e3 = __builtin_amdgcn_exp2f(s[nt][3]);
      den[nt] += (e0 + e1) + (e2 + e3);
      uint2 o; o.x = cvt_pk_bf16(e0, e1); o.y = cvt_pk_bf16(e2, e3);
      *(uint2*)&pt[nt*16 + lr][w*16 + q4*4] = o;
    }
    __syncthreads();

    // PV: acc2[8 a-tiles][d-stripe w]
    #pragma unroll
    for (int kk = 0; kk < 64; kk += 32){
      int kb = kk + q4 * 8;
      bf16x8 vf = *(const bf16x8*)&vt[w*16 + lr][kb];
      #pragma unroll
      for (int mt=0;mt<8;mt++){
        bf16x8 pf = *(const bf16x8*)&pt[mt*16 + lr][kb];
        acc2[mt] = mfma16(pf, vf, acc2[mt]);
      }
    }
  }

  // den: collapse q4 quarters, then cross-wave (waves own n-stripes)
  #pragma unroll
  for (int nt=0;nt<8;nt++){
    float r = den[nt];
    r += __shfl_xor(r, 16);
    r += __shfl_xor(r, 32);
    if (q4 == 0) dnf[w][nt*16 + lr] = r;
  }
  __syncthreads();

  size_t base = ((size_t)(h * 16 + ch) * 512 + a0) * 64;
  #pragma unroll
  for (int mt=0;mt<8;mt++)
    #pragma unroll
    for (int j=0;j<4;j++){
      int a = mt*16 + q4*4 + j;
      int d = w*16 + lr;
      nump[base + (size_t)a*64 + d] = acc2[mt][j];
    }
  if (t < 128)
    denp[(size_t)(h*16 + ch) * 512 + a0 + t] = dnf[0][t] + dnf[1][t] + dnf[2][t] + dnf[3][t];
}

// ---------------- reduce partials -> agent_v transposed [h][d][a] bf16 ----------
__global__ __launch_bounds__(64) void k_agent_reduce(const float* __restrict__ nump, const float* __restrict__ denp,
                                                     u16* __restrict__ avtg){
  int h = blockIdx.x >> 9;
  int a = blockIdx.x & 511;
  int d = threadIdx.x;
  float num = 0.f, den = 0.f;
  for (int c = 0; c < 16; c++){
    num += nump[((size_t)(h * 16 + c) * 512 + a) * 64 + d];
    den += denp[(size_t)(h * 16 + c) * 512 + a];
  }
  avtg[((size_t)h * 64 + d) * 512 + a] = f2bf(num / den);
}

// ---------------- query attention (pipelined): softmax_a(q*agent^T)*agent_v + v ----
// grid (256, 8). Q in regs; ag/avt/pt double-buffered; per iter ONE contiguous
// compute region {S(at), exp, P-write, PV(at-1)}, then barrier + stage-write.
__global__ __launch_bounds__(256) void k_qattn(const u16* __restrict__ qkv, const u16* __restrict__ agbf,
                                               const u16* __restrict__ avtg, u16* __restrict__ atto){
  int n0 = blockIdx.x * 64;
  int h  = blockIdx.y;
  __shared__ u16 agL[2][64][68];
  __shared__ u16 avL[2][64][68];
  __shared__ u16 pt[2][64][68];
  __shared__ float dnf[4][64];
  int t = threadIdx.x, w = t >> 6, l = t & 63;
  int lr = l & 15, q4 = l >> 4;

  // Q fragments in registers (B-operand of swapped S-mfma)
  bf16x8 qf[4][2];
  #pragma unroll
  for (int nt=0;nt<4;nt++)
    #pragma unroll
    for (int kk=0;kk<2;kk++)
      qf[nt][kk] = *(const bf16x8*)(qkv + (size_t)(n0 + nt*16 + lr) * 1536 + h*64 + kk*32 + q4*8);

  // staging: 32 B/thread per array (64 rows x 64 cols bf16 = 8 KB, 256 threads)
  int sr = t >> 2, sc = (t & 3) * 16;
  uint4 rg0, rg1, rv0, rv1;
  rg0 = *(const uint4*)(agbf + (size_t)(h*512 + sr) * 64 + sc);
  rg1 = *(const uint4*)(agbf + (size_t)(h*512 + sr) * 64 + sc + 8);
  rv0 = *(const uint4*)(avtg + (size_t)(h*64 + sr) * 512 + sc);
  rv1 = *(const uint4*)(avtg + (size_t)(h*64 + sr) * 512 + sc + 8);
  *(uint4*)&agL[0][sr][sc]     = rg0;
  *(uint4*)&agL[0][sr][sc + 8] = rg1;
  *(uint4*)&avL[0][sr][sc]     = rv0;
  *(uint4*)&avL[0][sr][sc + 8] = rv1;
  __syncthreads();

  f32x4 acc[4];
  #pragma unroll
  for (int i=0;i<4;i++) acc[i] = {0.f,0.f,0.f,0.f};
  float den[4] = {0.f,0.f,0.f,0.f};

  for (int at = 0; at < 8; at++){
    int cur = at & 1, prv = cur ^ 1;
    // issue next tile's global loads (in flight across the compute region)
    if (at + 1 < 8){
      rg0 = *(const uint4*)(agbf + (size_t)(h*512 + (at+1)*64 + sr) * 64 + sc);
      rg1 = *(const uint4*)(agbf + (size_t)(h*512 + (at+1)*64 + sr) * 64 + sc + 8);
      rv0 = *(const uint4*)(avtg + (size_t)(h*64 + sr) * 512 + (at+1)*64 + sc);
      rv1 = *(const uint4*)(avtg + (size_t)(h*64 + sr) * 512 + (at+1)*64 + sc + 8);
    }
    // S(at): af from agL[cur], qf regs
    f32x4 s[4];
    #pragma unroll
    for (int nt=0;nt<4;nt++) s[nt] = {0.f,0.f,0.f,0.f};
    #pragma unroll
    for (int kk = 0; kk < 2; kk++){
      bf16x8 af = *(const bf16x8*)&agL[cur][w*16 + lr][kk*32 + q4*8];
      #pragma unroll
      for (int nt=0;nt<4;nt++)
        s[nt] = mfma16(af, qf[nt][kk], s[nt]);
    }
    // exp2 + pack + den; write pt[cur]
    #pragma unroll
    for (int nt=0;nt<4;nt++){
      float e0 = __builtin_amdgcn_exp2f(s[nt][0]);
      float e1 = __builtin_amdgcn_exp2f(s[nt][1]);
      float e2 = __builtin_amdgcn_exp2f(s[nt][2]);
      float e3 = __builtin_amdgcn_exp2f(s[nt][3]);
      den[nt] += (e0 + e1) + (e2 + e3);
      uint2 o; o.x = cvt_pk_bf16(e0, e1); o.y = cvt_pk_bf16(e2, e3);
      *(uint2*)&pt[cur][nt*16 + lr][w*16 + q4*4] = o;
    }
    // PV(at-1): pt[prv], avL[prv]
    if (at > 0){
      #pragma unroll
      for (int kk = 0; kk < 64; kk += 32){
        int kb = kk + q4*8;
        bf16x8 vf = *(const bf16x8*)&avL[prv][w*16 + lr][kb];
        #pragma unroll
        for (int mt=0;mt<4;mt++){
          bf16x8 pf = *(const bf16x8*)&pt[prv][mt*16 + lr][kb];
          acc[mt] = mfma16(pf, vf, acc[mt]);
        }
      }
    }
    __syncthreads();            // prv-buffer reads done; pt[cur] visible
    if (at + 1 < 8){
      *(uint4*)&agL[prv][sr][sc]     = rg0;
      *(uint4*)&agL[prv][sr][sc + 8] = rg1;
      *(uint4*)&avL[prv][sr][sc]     = rv0;
      *(uint4*)&avL[prv][sr][sc + 8] = rv1;
    }
    __syncthreads();            // next tile staged
  }
  // tail: PV(7) from pt[1], avL[1]
  {
    #pragma unroll
    for (int kk = 0; kk < 64; kk += 32){
      int kb = kk + q4*8;
      bf16x8 vf = *(const bf16x8*)&avL[1][w*16 + lr][kb];
      #pragma unroll
      for (int mt=0;mt<4;mt++){
        bf16x8 pf = *(const bf16x8*)&pt[1][mt*16 + lr][kb];
        acc[mt] = mfma16(pf, vf, acc[mt]);
      }
    }
  }

  // denominator: reduce over q4 halves then across waves
  float dq[4];
  #pragma unroll
  for (int nt=0;nt<4;nt++){
    float r = den[nt];
    r += __shfl_xor(r, 16);
    r += __shfl_xor(r, 32);
    dq[nt] = r;
  }
  if (q4 == 0)
    #pragma unroll
    for (int nt=0;nt<4;nt++) dnf[w][nt*16 + lr] = dq[nt];
  __syncthreads();
  if (t < 64){
    float sden = dnf[0][t] + dnf[1][t] + dnf[2][t] + dnf[3][t];
    dnf[0][t] = __builtin_amdgcn_rcpf(sden);
  }
  __syncthreads();

  // epilogue: out = acc * (1/den) + v
  int d = w*16 + lr;
  #pragma unroll
  for (int mt=0;mt<4;mt++){
    #pragma unroll
    for (int j=0;j<4;j++){
      int n = mt*16 + q4*4 + j;
      float v = bf2f(qkv[(size_t)(n0 + n) * 1536 + 1024 + h * 64 + d]);
      atto[(size_t)(n0 + n) * 512 + h * 64 + d] = f2bf(acc[mt][j] * dnf[0][n] + v);
    }
  }
}

extern "C" void kernel_launch(void* const* d_in, const int* in_sizes, int n_in,
                              void* d_out, int out_size, void* d_ws, size_t ws_size,
                              hipStream_t stream) {
  const float* x     = (const float*)d_in[0];
  const float* gamma = (const float*)d_in[1];
  const float* beta  = (const float*)d_in[2];
  const float* w_qkv = (const float*)d_in[3];
  const float* agent = (const float*)d_in[4];
  const float* w_out = (const float*)d_in[5];
  const float* b_out = (const float*)d_in[6];
  float* y = (float*)d_out;

  char* ws = (char*)d_ws;
  // byte offsets (all 16B aligned)
  u16*   xn    = (u16*)  (ws + 0);            // 16384*512  bf16 = 16,777,216
  u16*   qkv   = (u16*)  (ws + 16777216);     // 16384*1536 bf16 = 50,331,648
  u16*   wqkvt = (u16*)  (ws + 67108864);     // 1536*512   bf16 =  1,572,864
  u16*   woutt = (u16*)  (ws + 68681728);     // 512*512    bf16 =    524,288
  u16*   agbf  = (u16*)  (ws + 69206016);     // 8*512*64   bf16 =    524,288  (pre-scaled by 0.125*log2e)
  u16*   avtg  = (u16*)  (ws + 69730304);     // 8*64*512   bf16 =    524,288
  u16*   vT    = (u16*)  (ws + 70254592);     // 8*64*16384 bf16 = 16,777,216 (dead before atto written)
  u16*   atto  = (u16*)  (ws + 70254592);     // 16384*512  bf16 = 16,777,216 (aliases vT; disjoint lifetime)
  float* nump  = (float*)(ws + 87031808);     // 8*16*512*64 f32 = 16,777,216
  float* denp  = (float*)(ws + 103809024);    // 8*16*512    f32 =    262,144

  // scale = (1/sqrt(64)) * log2(e), folded into agent so exp(s*scale) == exp2(S')
  k_conv_bf   <<<dim3(256),     dim3(256), 0, stream>>>(agent, agbf, 8*512*64, 0.125f * 1.44269504089f);
  k_transp    <<<dim3(24, 8),   dim3(256), 0, stream>>>(w_qkv, wqkvt, 512, 1536);
  k_transp    <<<dim3(8, 8),    dim3(256), 0, stream>>>(w_out, woutt, 512, 512);
  k_ln        <<<dim3(16384),   dim3(128), 0, stream>>>(x, gamma, beta, xn);
  k_gemm_qkv  <<<dim3(64, 12),  dim3(512), 0, stream>>>(xn, wqkvt, qkv, vT);
  k_agent_agg <<<dim3(512),     dim3(256), 0, stream>>>(agbf, qkv, vT, nump, denp);
  k_agent_reduce<<<dim3(4096),  dim3(64),  0, stream>>>(nump, denp, avtg);
  k_qattn     <<<dim3(256, 8),  dim3(256), 0, stream>>>(qkv, agbf, avtg, atto);
  k_gemm_out  <<<dim3(64, 4),   dim3(512), 0, stream>>>(atto, woutt, x, b_out, y);
}

// Round 18
// 153.560 us; speedup vs baseline: 1.1039x; 1.1039x over previous
//
#include <hip/hip_runtime.h>
#include <stdint.h>

typedef unsigned short u16;
typedef __attribute__((ext_vector_type(8))) short bf16x8;
typedef __attribute__((ext_vector_type(4))) float f32x4;

__device__ __forceinline__ float bf2f(u16 u){
  union { uint32_t i; float f; } v; v.i = ((uint32_t)u) << 16; return v.f;
}
__device__ __forceinline__ u16 f2bf(float f){
  union { float fl; uint32_t i; } v; v.fl = f;
  uint32_t r = v.i + 0x7FFFu + ((v.i >> 16) & 1u);
  return (u16)(r >> 16);
}
__device__ __forceinline__ uint32_t cvt_pk_bf16(float lo, float hi){
  uint32_t r;
  asm("v_cvt_pk_bf16_f32 %0, %1, %2" : "=v"(r) : "v"(lo), "v"(hi));
  return r;
}
__device__ __forceinline__ f32x4 mfma16(bf16x8 a, bf16x8 b, f32x4 c){
  return __builtin_amdgcn_mfma_f32_16x16x32_bf16(a, b, c, 0, 0, 0);
}
// async global->LDS, 16 B per lane; LDS dest is wave-uniform base + lane*16
__device__ __forceinline__ void gload16(const u16* g, u16* l){
  __builtin_amdgcn_global_load_lds((const __attribute__((address_space(1))) void*)g,
                                   (__attribute__((address_space(3))) void*)l, 16, 0, 0);
}

// ---------------- elementwise convert f32 -> bf16 (with scale fold) ----------------
__global__ __launch_bounds__(256) void k_conv_bf(const float* __restrict__ in, u16* __restrict__ out, int n, float scale){
  int i = (blockIdx.x * 256 + threadIdx.x) * 4;
  if (i >= n) return;
  float4 v = *(const float4*)(in + i);
  ushort4 o; o.x=f2bf(v.x*scale); o.y=f2bf(v.y*scale); o.z=f2bf(v.z*scale); o.w=f2bf(v.w*scale);
  *(ushort4*)(out + i) = o;
}

// ---------- transpose + convert: in[R][C] f32 -> out[C][R] bf16 ----------
__global__ __launch_bounds__(256) void k_transp(const float* __restrict__ in, u16* __restrict__ out, int R, int C){
  __shared__ u16 tile[64][68];
  int c0 = blockIdx.x * 64, r0 = blockIdx.y * 64;
  int tr = threadIdx.x >> 4;           // 0..15
  int tc = (threadIdx.x & 15) * 4;     // 0..60
  for (int rr = 0; rr < 4; rr++){
    int r = rr * 16 + tr;
    float4 v = *(const float4*)(in + (size_t)(r0 + r) * C + c0 + tc);
    ushort4 o; o.x=f2bf(v.x); o.y=f2bf(v.y); o.z=f2bf(v.z); o.w=f2bf(v.w);
    *(ushort4*)&tile[r][tc] = o;
  }
  __syncthreads();
  for (int rr = 0; rr < 4; rr++){
    int oc = rr * 16 + tr;             // original col = out row
    ushort4 o;
    o.x = tile[tc+0][oc]; o.y = tile[tc+1][oc]; o.z = tile[tc+2][oc]; o.w = tile[tc+3][oc];
    *(ushort4*)(out + (size_t)(c0 + oc) * R + r0 + tc) = o;
  }
}

// ---------------- LayerNorm: x[16384][512] f32 -> xn bf16 ----------------
__global__ __launch_bounds__(128) void k_ln(const float* __restrict__ x, const float* __restrict__ g,
                                            const float* __restrict__ b, u16* __restrict__ xn){
  int row = blockIdx.x;
  int t = threadIdx.x;
  float4 v = *(const float4*)(x + (size_t)row * 512 + t * 4);
  float s = v.x + v.y + v.z + v.w;
  float q = v.x*v.x + v.y*v.y + v.z*v.z + v.w*v.w;
  for (int o = 32; o > 0; o >>= 1){ s += __shfl_down(s, o); q += __shfl_down(q, o); }
  __shared__ float red[4];
  if ((t & 63) == 0){ red[(t >> 6) * 2] = s; red[(t >> 6) * 2 + 1] = q; }
  __syncthreads();
  float mu  = (red[0] + red[2]) * (1.0f/512.0f);
  float var = (red[1] + red[3]) * (1.0f/512.0f) - mu * mu;
  float rs = rsqrtf(var + 1e-5f);
  float4 gv = *(const float4*)(g + t * 4);
  float4 bv = *(const float4*)(b + t * 4);
  ushort4 o;
  o.x = f2bf((v.x - mu) * rs * gv.x + bv.x);
  o.y = f2bf((v.y - mu) * rs * gv.y + bv.y);
  o.z = f2bf((v.z - mu) * rs * gv.z + bv.z);
  o.w = f2bf((v.w - mu) * rs * gv.w + bv.w);
  *(ushort4*)(xn + (size_t)row * 512 + t * 4) = o;
}

// ======== 256x128-tile counted-vmcnt GEMM skeleton (8 waves, swizzled LDS) =====
// ------- QKV GEMM: C = A * Bt^T; V-third also scattered transposed into vT ------
__global__ __launch_bounds__(512) void k_gemm_qkv(const u16* __restrict__ A, const u16* __restrict__ Bt,
                                                  u16* __restrict__ C, u16* __restrict__ vT){
  __shared__ u16 aL[2][256 * 64];
  __shared__ u16 bL[2][128 * 64];
  int m0 = blockIdx.x * 256, n0 = blockIdx.y * 128;
  int t = threadIdx.x, w = t >> 6, l = t & 63;
  int wm = (w >> 1) * 64, wn = (w & 1) * 64;   // 4M x 2N wave grid
  int lr = l & 15;
  int blkSrc = (l & 7) ^ ((l >> 3) & 7);
  const u16* gA = A  + (size_t)(m0 + w*8 + (l >> 3)) * 512 + blkSrc * 8;
  const u16* gB = Bt + (size_t)(n0 + w*8 + (l >> 3)) * 512 + blkSrc * 8;
  f32x4 acc[4][4];
  for (int i=0;i<4;i++) for (int j=0;j<4;j++) acc[i][j] = {0.f,0.f,0.f,0.f};

  auto stage = [&](int buf, int k0){
    #pragma unroll
    for (int p = 0; p < 4; p++)
      gload16(gA + (size_t)p*64*512 + k0, &aL[buf][(p*64 + w*8) * 64]);
    #pragma unroll
    for (int p = 0; p < 2; p++)
      gload16(gB + (size_t)p*64*512 + k0, &bL[buf][(p*64 + w*8) * 64]);
  };
  auto comp = [&](const u16* ab, const u16* bb){
    #pragma unroll
    for (int kk = 0; kk < 64; kk += 32){
      int xo = (((l >> 4) + (kk >> 3)) ^ (l & 7)) << 3;  // swizzled 16B-block offset
      bf16x8 av[4], bv[4];
      #pragma unroll
      for (int mt=0;mt<4;mt++) av[mt] = *(const bf16x8*)&ab[(wm + mt*16 + lr)*64 + xo];
      #pragma unroll
      for (int nt=0;nt<4;nt++) bv[nt] = *(const bf16x8*)&bb[(wn + nt*16 + lr)*64 + xo];
      #pragma unroll
      for (int mt=0;mt<4;mt++)
        #pragma unroll
        for (int nt=0;nt<4;nt++)
          acc[mt][nt] = mfma16(av[mt], bv[nt], acc[mt][nt]);
    }
  };

  // prologue: tiles 0 and 1 in flight; wait only for tile 0 (oldest 6)
  stage(0, 0);
  stage(1, 64);
  asm volatile("s_waitcnt vmcnt(6)" ::: "memory");
  __builtin_amdgcn_s_barrier();
  asm volatile("" ::: "memory");
  int cur = 0;
  #pragma unroll
  for (int tk = 0; tk < 8; tk++){
    comp(&aL[cur][0], &bL[cur][0]);
    if (tk < 7){
      __builtin_amdgcn_s_barrier();            // all waves done reading cur
      if (tk + 2 < 8){
        stage(cur, (tk + 2) * 64);             // refill cur (6 new loads)
        asm volatile("s_waitcnt vmcnt(6)" ::: "memory");  // tile tk+1 landed
      } else {
        asm volatile("s_waitcnt vmcnt(0)" ::: "memory");  // last tile landed
      }
      __builtin_amdgcn_s_barrier();            // all waves' loads landed
      asm volatile("" ::: "memory");
    }
    cur ^= 1;
  }

  int rr = (l >> 4) * 4, cc = l & 15;
  bool isV = (n0 >= 1024);
  for (int mt=0;mt<4;mt++) for (int nt=0;nt<4;nt++){
    int r = m0 + wm + mt*16 + rr;
    int c = n0 + wn + nt*16 + cc;
    ushort4 o;
    o.x = f2bf(acc[mt][nt][0]); o.y = f2bf(acc[mt][nt][1]);
    o.z = f2bf(acc[mt][nt][2]); o.w = f2bf(acc[mt][nt][3]);
    C[(size_t)(r+0) * 1536 + c] = o.x;
    C[(size_t)(r+1) * 1536 + c] = o.y;
    C[(size_t)(r+2) * 1536 + c] = o.z;
    C[(size_t)(r+3) * 1536 + c] = o.w;
    if (isV) *(ushort4*)(vT + ((size_t)(c - 1024) << 14) + r) = o;
  }
}

// ------- out GEMM: y = A[16384][512]*Bt[512][512]^T + bias + x (f32) ----------
__global__ __launch_bounds__(512) void k_gemm_out(const u16* __restrict__ A, const u16* __restrict__ Bt,
                                                  const float* __restrict__ x, const float* __restrict__ bias,
                                                  float* __restrict__ y){
  __shared__ u16 aL[2][256 * 64];
  __shared__ u16 bL[2][128 * 64];
  int m0 = blockIdx.x * 256, n0 = blockIdx.y * 128;
  int t = threadIdx.x, w = t >> 6, l = t & 63;
  int wm = (w >> 1) * 64, wn = (w & 1) * 64;
  int lr = l & 15;
  int blkSrc = (l & 7) ^ ((l >> 3) & 7);
  const u16* gA = A  + (size_t)(m0 + w*8 + (l >> 3)) * 512 + blkSrc * 8;
  const u16* gB = Bt + (size_t)(n0 + w*8 + (l >> 3)) * 512 + blkSrc * 8;
  f32x4 acc[4][4];
  for (int i=0;i<4;i++) for (int j=0;j<4;j++) acc[i][j] = {0.f,0.f,0.f,0.f};

  auto stage = [&](int buf, int k0){
    #pragma unroll
    for (int p = 0; p < 4; p++)
      gload16(gA + (size_t)p*64*512 + k0, &aL[buf][(p*64 + w*8) * 64]);
    #pragma unroll
    for (int p = 0; p < 2; p++)
      gload16(gB + (size_t)p*64*512 + k0, &bL[buf][(p*64 + w*8) * 64]);
  };
  auto comp = [&](const u16* ab, const u16* bb){
    #pragma unroll
    for (int kk = 0; kk < 64; kk += 32){
      int xo = (((l >> 4) + (kk >> 3)) ^ (l & 7)) << 3;
      bf16x8 av[4], bv[4];
      #pragma unroll
      for (int mt=0;mt<4;mt++) av[mt] = *(const bf16x8*)&ab[(wm + mt*16 + lr)*64 + xo];
      #pragma unroll
      for (int nt=0;nt<4;nt++) bv[nt] = *(const bf16x8*)&bb[(wn + nt*16 + lr)*64 + xo];
      #pragma unroll
      for (int mt=0;mt<4;mt++)
        #pragma unroll
        for (int nt=0;nt<4;nt++)
          acc[mt][nt] = mfma16(av[mt], bv[nt], acc[mt][nt]);
    }
  };

  stage(0, 0);
  stage(1, 64);
  asm volatile("s_waitcnt vmcnt(6)" ::: "memory");
  __builtin_amdgcn_s_barrier();
  asm volatile("" ::: "memory");
  int cur = 0;
  #pragma unroll
  for (int tk = 0; tk < 8; tk++){
    comp(&aL[cur][0], &bL[cur][0]);
    if (tk < 7){
      __builtin_amdgcn_s_barrier();
      if (tk + 2 < 8){
        stage(cur, (tk + 2) * 64);
        asm volatile("s_waitcnt vmcnt(6)" ::: "memory");
      } else {
        asm volatile("s_waitcnt vmcnt(0)" ::: "memory");
      }
      __builtin_amdgcn_s_barrier();
      asm volatile("" ::: "memory");
    }
    cur ^= 1;
  }

  int rr = (l >> 4) * 4, cc = l & 15;
  for (int mt=0;mt<4;mt++) for (int nt=0;nt<4;nt++)
    for (int j=0;j<4;j++){
      int r = m0 + wm + mt*16 + rr + j;
      int c = n0 + wn + nt*16 + cc;
      y[(size_t)r * 512 + c] = acc[mt][nt][j] + bias[c] + x[(size_t)r * 512 + c];
    }
}

// ------- agent aggregation (attn1 + agent_v): single-buffer, [68] pads, reg-den ----
// 1024 blocks; swizzled so the 8 atile-blocks of one (h,chunk) share an XCD.
// 36 KB LDS -> ~4 blocks/CU; TLP hides stage latency (m114).
__global__ __launch_bounds__(256) void k_agent_agg(const u16* __restrict__ agbf, const u16* __restrict__ qkv,
                                                   const u16* __restrict__ vT,
                                                   float* __restrict__ nump, float* __restrict__ denp){
  int L = blockIdx.x;
  int g = (L >> 6) * 8 + (L & 7);      // group = h*16 + ch  (same K/V panel)
  int m = (L >> 3) & 7;                // atile
  int h = g >> 4, ch = g & 15, a0 = m * 64;

  __shared__ u16 ag[64][68];
  __shared__ u16 kt[64][68];
  __shared__ u16 vt[64][68];
  __shared__ u16 pt[64][68];
  __shared__ float dnf[4][64];
  int t = threadIdx.x, w = t >> 6, l = t & 63;
  int lr = l & 15, q4 = l >> 4;

  // agent tile: loaded once ([68] rows, sr/sc map)
  int sr = t >> 2, sc = (t & 3) * 16;
  {
    uint4 a0v = *(const uint4*)(agbf + (size_t)(h * 512 + a0 + sr) * 64 + sc);
    uint4 a1v = *(const uint4*)(agbf + (size_t)(h * 512 + a0 + sr) * 64 + sc + 8);
    *(uint4*)&ag[sr][sc]     = a0v;
    *(uint4*)&ag[sr][sc + 8] = a1v;
  }

  size_t nbase = (size_t)ch * 1024;
  const u16* kp = qkv + 512 + h * 64;
  const u16* vp = vT + ((size_t)(h * 64 + sr) << 14);

  f32x4 acc2[4];                       // C[a][d], wave owns d-stripe w*16
  #pragma unroll
  for (int i=0;i<4;i++) acc2[i] = {0.f,0.f,0.f,0.f};
  float den[4] = {0.f,0.f,0.f,0.f};    // per-lane den partials (a = nt*16+lr)

  for (int sub = 0; sub < 16; sub++){
    size_t n0 = nbase + sub * 64;
    __syncthreads();                   // protect kt/vt/pt from previous readers
    {
      uint4 rk0 = *(const uint4*)(kp + (n0 + sr) * 1536 + sc);
      uint4 rk1 = *(const uint4*)(kp + (n0 + sr) * 1536 + sc + 8);
      uint4 rv0 = *(const uint4*)(vp + n0 + sc);
      uint4 rv1 = *(const uint4*)(vp + n0 + sc + 8);
      *(uint4*)&kt[sr][sc]     = rk0;
      *(uint4*)&kt[sr][sc + 8] = rk1;
      *(uint4*)&vt[sr][sc]     = rv0;
      *(uint4*)&vt[sr][sc + 8] = rv1;
    }
    __syncthreads();

    // S^T: a = nt*16+lr (col), n = w*16 + q4*4 + j (row)
    f32x4 s[4];
    #pragma unroll
    for (int nt=0;nt<4;nt++) s[nt] = {0.f,0.f,0.f,0.f};
    #pragma unroll
    for (int kk = 0; kk < 64; kk += 32){
      int kb = kk + q4 * 8;
      bf16x8 kf = *(const bf16x8*)&kt[w*16 + lr][kb];
      #pragma unroll
      for (int nt=0;nt<4;nt++){
        bf16x8 af = *(const bf16x8*)&ag[nt*16 + lr][kb];
        s[nt] = mfma16(kf, af, s[nt]);
      }
    }
    // exp2 + pack -> pt[a][n]; den accumulates in f32 regs
    #pragma unroll
    for (int nt=0;nt<4;nt++){
      float e0 = __builtin_amdgcn_exp2f(s[nt][0]);
      float e1 = __builtin_amdgcn_exp2f(s[nt][1]);
      float e2 = __builtin_amdgcn_exp2f(s[nt][2]);
      float e3 = __builtin_amdgcn_exp2f(s[nt][3]);
      den[nt] += (e0 + e1) + (e2 + e3);
      uint2 o; o.x = cvt_pk_bf16(e0, e1); o.y = cvt_pk_bf16(e2, e3);
      *(uint2*)&pt[nt*16 + lr][w*16 + q4*4] = o;
    }
    __syncthreads();

    // PV: acc2[a-tiles][d-stripe w]
    #pragma unroll
    for (int kk = 0; kk < 64; kk += 32){
      int kb = kk + q4 * 8;
      bf16x8 vf = *(const bf16x8*)&vt[w*16 + lr][kb];
      #pragma unroll
      for (int mt=0;mt<4;mt++){
        bf16x8 pf = *(const bf16x8*)&pt[mt*16 + lr][kb];
        acc2[mt] = mfma16(pf, vf, acc2[mt]);
      }
    }
  }

  // den: collapse q4 quarters, then cross-wave (waves own n-stripes)
  #pragma unroll
  for (int nt=0;nt<4;nt++){
    float r = den[nt];
    r += __shfl_xor(r, 16);
    r += __shfl_xor(r, 32);
    if (q4 == 0) dnf[w][nt*16 + lr] = r;
  }
  __syncthreads();

  size_t base = ((size_t)(h * 16 + ch) * 512 + a0) * 64;
  #pragma unroll
  for (int mt=0;mt<4;mt++)
    #pragma unroll
    for (int j=0;j<4;j++){
      int a = mt*16 + q4*4 + j;
      int d = w*16 + lr;
      nump[base + (size_t)a*64 + d] = acc2[mt][j];
    }
  if (t < 64)
    denp[(size_t)(h*16 + ch) * 512 + a0 + t] = dnf[0][t] + dnf[1][t] + dnf[2][t] + dnf[3][t];
}

// ---------------- reduce partials -> agent_v transposed [h][d][a] bf16 ----------
__global__ __launch_bounds__(64) void k_agent_reduce(const float* __restrict__ nump, const float* __restrict__ denp,
                                                     u16* __restrict__ avtg){
  int h = blockIdx.x >> 9;
  int a = blockIdx.x & 511;
  int d = threadIdx.x;
  float num = 0.f, den = 0.f;
  for (int c = 0; c < 16; c++){
    num += nump[((size_t)(h * 16 + c) * 512 + a) * 64 + d];
    den += denp[(size_t)(h * 16 + c) * 512 + a];
  }
  avtg[((size_t)h * 64 + d) * 512 + a] = f2bf(num / den);
}

// ---------------- query attention (pipelined): softmax_a(q*agent^T)*agent_v + v ----
// grid (256, 8). Q in regs; ag/avt/pt double-buffered; per iter ONE contiguous
// compute region {S(at), exp, P-write, PV(at-1)}, then barrier + stage-write.
__global__ __launch_bounds__(256) void k_qattn(const u16* __restrict__ qkv, const u16* __restrict__ agbf,
                                               const u16* __restrict__ avtg, u16* __restrict__ atto){
  int n0 = blockIdx.x * 64;
  int h  = blockIdx.y;
  __shared__ u16 agL[2][64][68];
  __shared__ u16 avL[2][64][68];
  __shared__ u16 pt[2][64][68];
  __shared__ float dnf[4][64];
  int t = threadIdx.x, w = t >> 6, l = t & 63;
  int lr = l & 15, q4 = l >> 4;

  // Q fragments in registers (B-operand of swapped S-mfma)
  bf16x8 qf[4][2];
  #pragma unroll
  for (int nt=0;nt<4;nt++)
    #pragma unroll
    for (int kk=0;kk<2;kk++)
      qf[nt][kk] = *(const bf16x8*)(qkv + (size_t)(n0 + nt*16 + lr) * 1536 + h*64 + kk*32 + q4*8);

  // staging: 32 B/thread per array (64 rows x 64 cols bf16 = 8 KB, 256 threads)
  int sr = t >> 2, sc = (t & 3) * 16;
  uint4 rg0, rg1, rv0, rv1;
  rg0 = *(const uint4*)(agbf + (size_t)(h*512 + sr) * 64 + sc);
  rg1 = *(const uint4*)(agbf + (size_t)(h*512 + sr) * 64 + sc + 8);
  rv0 = *(const uint4*)(avtg + (size_t)(h*64 + sr) * 512 + sc);
  rv1 = *(const uint4*)(avtg + (size_t)(h*64 + sr) * 512 + sc + 8);
  *(uint4*)&agL[0][sr][sc]     = rg0;
  *(uint4*)&agL[0][sr][sc + 8] = rg1;
  *(uint4*)&avL[0][sr][sc]     = rv0;
  *(uint4*)&avL[0][sr][sc + 8] = rv1;
  __syncthreads();

  f32x4 acc[4];
  #pragma unroll
  for (int i=0;i<4;i++) acc[i] = {0.f,0.f,0.f,0.f};
  float den[4] = {0.f,0.f,0.f,0.f};

  for (int at = 0; at < 8; at++){
    int cur = at & 1, prv = cur ^ 1;
    // issue next tile's global loads (in flight across the compute region)
    if (at + 1 < 8){
      rg0 = *(const uint4*)(agbf + (size_t)(h*512 + (at+1)*64 + sr) * 64 + sc);
      rg1 = *(const uint4*)(agbf + (size_t)(h*512 + (at+1)*64 + sr) * 64 + sc + 8);
      rv0 = *(const uint4*)(avtg + (size_t)(h*64 + sr) * 512 + (at+1)*64 + sc);
      rv1 = *(const uint4*)(avtg + (size_t)(h*64 + sr) * 512 + (at+1)*64 + sc + 8);
    }
    // S(at): af from agL[cur], qf regs
    f32x4 s[4];
    #pragma unroll
    for (int nt=0;nt<4;nt++) s[nt] = {0.f,0.f,0.f,0.f};
    #pragma unroll
    for (int kk = 0; kk < 2; kk++){
      bf16x8 af = *(const bf16x8*)&agL[cur][w*16 + lr][kk*32 + q4*8];
      #pragma unroll
      for (int nt=0;nt<4;nt++)
        s[nt] = mfma16(af, qf[nt][kk], s[nt]);
    }
    // exp2 + pack + den; write pt[cur]
    #pragma unroll
    for (int nt=0;nt<4;nt++){
      float e0 = __builtin_amdgcn_exp2f(s[nt][0]);
      float e1 = __builtin_amdgcn_exp2f(s[nt][1]);
      float e2 = __builtin_amdgcn_exp2f(s[nt][2]);
      float e3 = __builtin_amdgcn_exp2f(s[nt][3]);
      den[nt] += (e0 + e1) + (e2 + e3);
      uint2 o; o.x = cvt_pk_bf16(e0, e1); o.y = cvt_pk_bf16(e2, e3);
      *(uint2*)&pt[cur][nt*16 + lr][w*16 + q4*4] = o;
    }
    // PV(at-1): pt[prv], avL[prv]
    if (at > 0){
      #pragma unroll
      for (int kk = 0; kk < 64; kk += 32){
        int kb = kk + q4*8;
        bf16x8 vf = *(const bf16x8*)&avL[prv][w*16 + lr][kb];
        #pragma unroll
        for (int mt=0;mt<4;mt++){
          bf16x8 pf = *(const bf16x8*)&pt[prv][mt*16 + lr][kb];
          acc[mt] = mfma16(pf, vf, acc[mt]);
        }
      }
    }
    __syncthreads();            // prv-buffer reads done; pt[cur] visible
    if (at + 1 < 8){
      *(uint4*)&agL[prv][sr][sc]     = rg0;
      *(uint4*)&agL[prv][sr][sc + 8] = rg1;
      *(uint4*)&avL[prv][sr][sc]     = rv0;
      *(uint4*)&avL[prv][sr][sc + 8] = rv1;
    }
    __syncthreads();            // next tile staged
  }
  // tail: PV(7) from pt[1], avL[1]
  {
    #pragma unroll
    for (int kk = 0; kk < 64; kk += 32){
      int kb = kk + q4*8;
      bf16x8 vf = *(const bf16x8*)&avL[1][w*16 + lr][kb];
      #pragma unroll
      for (int mt=0;mt<4;mt++){
        bf16x8 pf = *(const bf16x8*)&pt[1][mt*16 + lr][kb];
        acc[mt] = mfma16(pf, vf, acc[mt]);
      }
    }
  }

  // denominator: reduce over q4 halves then across waves
  float dq[4];
  #pragma unroll
  for (int nt=0;nt<4;nt++){
    float r = den[nt];
    r += __shfl_xor(r, 16);
    r += __shfl_xor(r, 32);
    dq[nt] = r;
  }
  if (q4 == 0)
    #pragma unroll
    for (int nt=0;nt<4;nt++) dnf[w][nt*16 + lr] = dq[nt];
  __syncthreads();
  if (t < 64){
    float sden = dnf[0][t] + dnf[1][t] + dnf[2][t] + dnf[3][t];
    dnf[0][t] = __builtin_amdgcn_rcpf(sden);
  }
  __syncthreads();

  // epilogue: out = acc * (1/den) + v
  int d = w*16 + lr;
  #pragma unroll
  for (int mt=0;mt<4;mt++){
    #pragma unroll
    for (int j=0;j<4;j++){
      int n = mt*16 + q4*4 + j;
      float v = bf2f(qkv[(size_t)(n0 + n) * 1536 + 1024 + h * 64 + d]);
      atto[(size_t)(n0 + n) * 512 + h * 64 + d] = f2bf(acc[mt][j] * dnf[0][n] + v);
    }
  }
}

extern "C" void kernel_launch(void* const* d_in, const int* in_sizes, int n_in,
                              void* d_out, int out_size, void* d_ws, size_t ws_size,
                              hipStream_t stream) {
  const float* x     = (const float*)d_in[0];
  const float* gamma = (const float*)d_in[1];
  const float* beta  = (const float*)d_in[2];
  const float* w_qkv = (const float*)d_in[3];
  const float* agent = (const float*)d_in[4];
  const float* w_out = (const float*)d_in[5];
  const float* b_out = (const float*)d_in[6];
  float* y = (float*)d_out;

  char* ws = (char*)d_ws;
  // byte offsets (all 16B aligned)
  u16*   xn    = (u16*)  (ws + 0);            // 16384*512  bf16 = 16,777,216
  u16*   qkv   = (u16*)  (ws + 16777216);     // 16384*1536 bf16 = 50,331,648
  u16*   wqkvt = (u16*)  (ws + 67108864);     // 1536*512   bf16 =  1,572,864
  u16*   woutt = (u16*)  (ws + 68681728);     // 512*512    bf16 =    524,288
  u16*   agbf  = (u16*)  (ws + 69206016);     // 8*512*64   bf16 =    524,288  (pre-scaled by 0.125*log2e)
  u16*   avtg  = (u16*)  (ws + 69730304);     // 8*64*512   bf16 =    524,288
  u16*   vT    = (u16*)  (ws + 70254592);     // 8*64*16384 bf16 = 16,777,216 (dead before atto written)
  u16*   atto  = (u16*)  (ws + 70254592);     // 16384*512  bf16 = 16,777,216 (aliases vT; disjoint lifetime)
  float* nump  = (float*)(ws + 87031808);     // 8*16*512*64 f32 = 16,777,216
  float* denp  = (float*)(ws + 103809024);    // 8*16*512    f32 =    262,144

  // scale = (1/sqrt(64)) * log2(e), folded into agent so exp(s*scale) == exp2(S')
  k_conv_bf   <<<dim3(256),     dim3(256), 0, stream>>>(agent, agbf, 8*512*64, 0.125f * 1.44269504089f);
  k_transp    <<<dim3(24, 8),   dim3(256), 0, stream>>>(w_qkv, wqkvt, 512, 1536);
  k_transp    <<<dim3(8, 8),    dim3(256), 0, stream>>>(w_out, woutt, 512, 512);
  k_ln        <<<dim3(16384),   dim3(128), 0, stream>>>(x, gamma, beta, xn);
  k_gemm_qkv  <<<dim3(64, 12),  dim3(512), 0, stream>>>(xn, wqkvt, qkv, vT);
  k_agent_agg <<<dim3(1024),    dim3(256), 0, stream>>>(agbf, qkv, vT, nump, denp);
  k_agent_reduce<<<dim3(4096),  dim3(64),  0, stream>>>(nump, denp, avtg);
  k_qattn     <<<dim3(256, 8),  dim3(256), 0, stream>>>(qkv, agbf, avtg, atto);
  k_gemm_out  <<<dim3(64, 4),   dim3(512), 0, stream>>>(atto, woutt, x, b_out, y);
}